// Round 11
// baseline (492.968 us; speedup 1.0000x reference)
//
#include <hip/hip_runtime.h>
#include <math.h>

#define NPTS 16384
#define KNB  16
#define D    512
#define NCHAIN 194   // 128 hop blocks + 66 fstep blocks; <=256 => co-resident

// ---------------------------------------------------------------------------
// Closed-form restructure (verified rounds 1-10, absmax 0.0625). With
// S = gather-mean, R = Wres^T + I, M' = (W2c*W1)^T, per-block map
// f' = Cb + S^2 f M' + f R (f0 = 0), tracked in [33,512] coefficient space
// (rows 4k+c = component c of s_k, row 32 = bias):
//   F_1 = Cb33,   F_{t+1} = Cb33 + Shift2(F_t)*M' + F_t*R,   Ecat = F_4
// Final: out = [s0..s7,1] ([N,33]) x Ecat.
// Round 11: round-10 structure (3 dispatches: prep -> chain -> out) with the
// barrier poll fixed: RMW-poll (atomicAdd(cnt,0) — exclusive-ownership
// ping-pong across 8 XCDs, ~74us/barrier) replaced by a device-scope relaxed
// LOAD poll (reads share the line at LLC; only 194 RMW increments total).
// ---------------------------------------------------------------------------

__device__ __forceinline__ float4 red16(float ax, float ay, float az,
                                        float aw) {
#pragma unroll
  for (int o = 1; o < 16; o <<= 1) {
    ax += __shfl_xor(ax, o, 64); ay += __shfl_xor(ay, o, 64);
    az += __shfl_xor(az, o, 64); aw += __shfl_xor(aw, o, 64);
  }
  return make_float4(ax, ay, az, aw);
}

// 1-hop gather-mean, 16 threads/point (t < 262144)
__device__ __forceinline__ void onehop16(int t, const int* __restrict__ knn,
                                         const float4* __restrict__ in,
                                         float4* __restrict__ out) {
  int n = t >> 4, k = t & 15;
  float4 g = in[knn[n * KNB + k]];
  float4 s = red16(g.x, g.y, g.z, g.w);
  if (k == 0) {
    const float r = 1.f / 16.f;
    out[n] = make_float4(s.x * r, s.y * r, s.z * r, s.w * r);
  }
}

// Global barrier: tid0-only. Release fence + ONE atomicAdd per block, then a
// device-scope relaxed LOAD poll (no RMW ping-pong), s_sleep between polls.
__device__ __forceinline__ void gbarrier(int* __restrict__ cnt, int target) {
  __syncthreads();  // all block stores issued & drained
  if (threadIdx.x == 0) {
    __threadfence();  // release: push dirty lines to coherence point
    __hip_atomic_fetch_add(cnt, 1, __ATOMIC_RELEASE,
                           __HIP_MEMORY_SCOPE_AGENT);
    while (__hip_atomic_load(cnt, __ATOMIC_RELAXED,
                             __HIP_MEMORY_SCOPE_AGENT) < target)
      __builtin_amdgcn_s_sleep(16);
  }
  __syncthreads();
  __threadfence();  // acquire: invalidate stale cached lines
}

// One Horner step, 66-block layout: block fb handles row r = fb>>1,
// cols jbase..jbase+255 (jbase = (fb&1)*256). 1024 thr = 256 cols x 4
// K-chunks of 128; LDS reduce. fp64 accumulate (verified numerics).
__device__ __forceinline__ void fstep66(
    int fb, int tid, int first, const float* __restrict__ Fprev,
    const float* __restrict__ zbuf, const float* __restrict__ Rm,
    const float* __restrict__ Mt, float* __restrict__ Fnext) {
  __shared__ double sA[512], sB[512];
  __shared__ double redm[4][256];
  const int r = fb >> 1, jbase = (fb & 1) * 256;
  const int rm = (r >= 8 && r < 32) ? (r - 8) : (r == 32 ? 32 : -1);
  if (tid < 512) {
    float v = first
        ? ((r < 8) ? zbuf[r * D + tid] : (r == 32 ? zbuf[8 * D + tid] : 0.f))
        : Fprev[r * D + tid];
    sA[tid] = (double)v;
  } else {
    int kk = tid - 512;
    float v = 0.f;
    if (rm >= 0)
      v = first ? ((rm < 8) ? zbuf[rm * D + kk]
                            : (rm == 32 ? zbuf[8 * D + kk] : 0.f))
                : Fprev[rm * D + kk];
    sB[kk] = (double)v;
  }
  __syncthreads();
  const int ol = tid & 255, kc = tid >> 8;
  const int j = jbase + ol, k0 = kc * 128;
  double a0 = 0.0, a1 = 0.0;
  for (int k = 0; k < 128; k += 2) {
    a0 += sA[k0 + k] * (double)Rm[(size_t)(k0 + k) * D + j] +
          sB[k0 + k] * (double)Mt[(size_t)(k0 + k) * D + j];
    a1 += sA[k0 + k + 1] * (double)Rm[(size_t)(k0 + k + 1) * D + j] +
          sB[k0 + k + 1] * (double)Mt[(size_t)(k0 + k + 1) * D + j];
  }
  redm[kc][ol] = a0 + a1;
  __syncthreads();
  if (kc == 0) {
    double s = redm[0][ol] + redm[1][ol] + redm[2][ol] + redm[3][ol];
    float cb = (r < 8) ? zbuf[r * D + j] : (r == 32 ? zbuf[8 * D + j] : 0.f);
    Fnext[r * D + j] = (float)(s + (double)cb);
  }
  __syncthreads();  // protect sA/sB for next stage's reload
}

// ---- L0: knn normalize | geo (16 thr/pt) | pq(z) | Mt | Rm | zero cnt ----
__global__ __launch_bounds__(256) void prep_kernel(
    const float* __restrict__ pts, const int* __restrict__ raw,
    const float* __restrict__ w_mlp1, const float* __restrict__ b_mlp1,
    const float* __restrict__ w_lfa1, const float* __restrict__ b_lfa1,
    const float* __restrict__ w_lfa2, const float* __restrict__ b_lfa2,
    const float* __restrict__ w_mlp2, const float* __restrict__ b_mlp2,
    const float* __restrict__ w_res, const float* __restrict__ b_res,
    int* __restrict__ knn_i, float4* __restrict__ sbase,
    float* __restrict__ zbuf, float* __restrict__ Mt,
    float* __restrict__ Rm, int* __restrict__ cnt) {
  // int64 little-endian => odd words are zero high halves; (1/16384)^4 FP risk
  const bool is64 = (raw[1] == 0) && (raw[3] == 0) && (raw[5] == 0) &&
                    (raw[7] == 0);
  const int t = blockIdx.x * 256 + threadIdx.x;  // < 262144 == D*D
  if (t < 8) cnt[t] = 0;  // barrier counters for chain_kernel
  knn_i[t] = is64 ? raw[2 * t] : raw[t];
  {  // geo: 16 threads/point
    int n = t >> 4, k = t & 15;
    int idx = is64 ? raw[2 * (n * KNB + k)] : raw[n * KNB + k];
    float dx = pts[n * 3 + 0] - pts[idx * 3 + 0];
    float dy = pts[n * 3 + 1] - pts[idx * 3 + 1];
    float dz = pts[n * 3 + 2] - pts[idx * 3 + 2];
    float nr = sqrtf(dx * dx + dy * dy + dz * dz);
    float4 s = red16(dx, dy, dz, nr);
    if (k == 0) {
      const float r = 1.f / 16.f;
      sbase[n] = make_float4(s.x * r, s.y * r, s.z * r, s.w * r);
    }
  }
  if (t < 32768) {  // pq: one wave per output column j; fp64 accumulate
    int j = t >> 6, lane = t & 63;
    const float* wrow = w_mlp2 + (size_t)j * D;
    double acc[9];
#pragma unroll
    for (int u = 0; u < 9; ++u) acc[u] = 0.0;
#pragma unroll
    for (int it = 0; it < 8; ++it) {
      int i = lane + 64 * it;
      double w = wrow[i];
      if (i < 256) {
        acc[0] += w * w_lfa2[i * 4 + 0]; acc[1] += w * w_lfa2[i * 4 + 1];
        acc[2] += w * w_lfa2[i * 4 + 2]; acc[3] += w * w_lfa2[i * 4 + 3];
        acc[8] += w * b_lfa2[i];
      } else if (i < 384) {
        int q = i - 256;
        acc[4] += w * w_lfa1[q * 4 + 0]; acc[5] += w * w_lfa1[q * 4 + 1];
        acc[6] += w * w_lfa1[q * 4 + 2]; acc[7] += w * w_lfa1[q * 4 + 3];
        acc[8] += w * b_lfa1[q];
      } else {
        acc[8] += w * b_mlp1[i - 384];
      }
    }
#pragma unroll
    for (int u = 0; u < 9; ++u) {
      double v = acc[u];
#pragma unroll
      for (int o = 32; o > 0; o >>= 1) v += __shfl_down(v, o, 64);
      if (lane == 0) {
        if (u == 8) v += (double)b_mlp2[j] + (double)b_res[j];
        zbuf[u * D + j] = (float)v;
      }
    }
  }
  {  // Mt[a*D+b] = sum_{i<128} w_mlp2[b][384+i]*w_mlp1[i][a]  (fp64 acc)
    int a = t & 511, b = t >> 9;
    const float* wrow = w_mlp2 + (size_t)b * D + 384;
    double s0 = 0.0, s1 = 0.0, s2 = 0.0, s3 = 0.0;
#pragma unroll 8
    for (int i = 0; i < 128; i += 4) {
      s0 += (double)wrow[i + 0] * (double)w_mlp1[(size_t)(i + 0) * D + a];
      s1 += (double)wrow[i + 1] * (double)w_mlp1[(size_t)(i + 1) * D + a];
      s2 += (double)wrow[i + 2] * (double)w_mlp1[(size_t)(i + 2) * D + a];
      s3 += (double)wrow[i + 3] * (double)w_mlp1[(size_t)(i + 3) * D + a];
    }
    Mt[(size_t)a * D + b] = (float)((s0 + s1) + (s2 + s3));
  }
  {  // Rm[i*D+j] = w_res[j][i] + (i==j)
    int i = t & 511, j = t >> 9;
    Rm[(size_t)i * D + j] = w_res[(size_t)j * D + i] + ((i == j) ? 1.0f : 0.0f);
  }
}

// ---- L1: s1..s6 (hop blocks 0..127) + fstep1..3 (blocks 128..193),
//          5 load-poll global barriers ----
__global__ __launch_bounds__(1024, 4) void chain_kernel(
    const int* __restrict__ knn, float4* __restrict__ sbase,
    const float* __restrict__ zbuf, const float* __restrict__ Rm,
    const float* __restrict__ Mt, float* __restrict__ F2,
    float* __restrict__ F3, float* __restrict__ Ecat, int* __restrict__ cnt) {
  const int tid = threadIdx.x;
  const bool isHop = blockIdx.x < 128;
  const float* fins[3] = {nullptr, F2, F3};
  float* fouts[3] = {F2, F3, Ecat};
  for (int ph = 0; ph < 6; ++ph) {
    if (isHop) {
      const float4* sin = sbase + (size_t)ph * NPTS;
      float4* sout = sbase + (size_t)(ph + 1) * NPTS;
      onehop16(blockIdx.x * 2048 + tid, knn, sin, sout);
      onehop16(blockIdx.x * 2048 + 1024 + tid, knn, sin, sout);
    } else if (ph < 3) {
      fstep66((int)blockIdx.x - 128, tid, ph == 0, fins[ph], zbuf, Rm, Mt,
              fouts[ph]);
    }
    if (ph < 5) gbarrier(cnt + ph, NCHAIN);
  }
}

// ---- L2: out[n][:] = [s0..s7,1][n] x Ecat; s7 inline (1-hop from s6) ----
__global__ __launch_bounds__(1024, 4) void out_kernel(
    const int* __restrict__ knn, const float4* __restrict__ sbase,
    const float* __restrict__ Ecat, float* __restrict__ outp) {
  const int tid = threadIdx.x;
  const int n0 = blockIdx.x * 64;
  __shared__ float4 s_t[8][64];
  {  // s7 for this block's 64 points: 16 threads/point
    int pt = tid >> 4, k = tid & 15;
    float4 g = sbase[(size_t)6 * NPTS + knn[(n0 + pt) * KNB + k]];
    float4 s = red16(g.x, g.y, g.z, g.w);
    if (k == 0) {
      const float r = 1.f / 16.f;
      s_t[7][pt] = make_float4(s.x * r, s.y * r, s.z * r, s.w * r);
    }
  }
  if (tid < 448) {  // load s0..s6 tiles
    int k = tid / 64, pt = tid & 63;
    s_t[k][pt] = sbase[(size_t)k * NPTS + n0 + pt];
  }
  __syncthreads();
  const int col2 = tid & 255;  // this thread's float2 column
  const int ptg = tid >> 8;    // 0..3
  float2 tab[33];
#pragma unroll
  for (int r = 0; r < 33; ++r)
    tab[r] = *(const float2*)(Ecat + r * D + col2 * 2);
#pragma unroll
  for (int it = 0; it < 16; ++it) {
    int pt = ptg * 16 + it;
    float2 acc = tab[32];
#pragma unroll
    for (int k = 0; k < 8; ++k) {
      float4 s = s_t[k][pt];  // wave-uniform LDS broadcast
      float2 e0 = tab[4 * k + 0], e1 = tab[4 * k + 1];
      float2 e2 = tab[4 * k + 2], e3 = tab[4 * k + 3];
      acc.x += s.x * e0.x + s.y * e1.x + s.z * e2.x + s.w * e3.x;
      acc.y += s.x * e0.y + s.y * e1.y + s.z * e2.y + s.w * e3.y;
    }
    *(float2*)(outp + (size_t)(n0 + pt) * D + col2 * 2) = acc;
  }
}

extern "C" void kernel_launch(void* const* d_in, const int* in_sizes, int n_in,
                              void* d_out, int out_size, void* d_ws,
                              size_t ws_size, hipStream_t stream) {
  const float* inputs = (const float*)d_in[0];
  const int* knn_raw  = (const int*)d_in[1];
  const float* w_mlp1 = (const float*)d_in[2];
  const float* b_mlp1 = (const float*)d_in[3];
  const float* w_lfa1 = (const float*)d_in[4];
  const float* b_lfa1 = (const float*)d_in[5];
  const float* w_lfa2 = (const float*)d_in[6];
  const float* b_lfa2 = (const float*)d_in[7];
  const float* w_mlp2 = (const float*)d_in[8];
  const float* b_mlp2 = (const float*)d_in[9];
  const float* w_res  = (const float*)d_in[10];
  const float* b_res  = (const float*)d_in[11];
  float* out = (float*)d_out;

  // workspace (floats): ~5.5 MB
  float*  ws    = (float*)d_ws;
  float4* sbase = (float4*)(ws + 0);          // 8 * 16384 float4
  float*  zbuf  = ws + 524288;                // 9 * 512
  float*  F2    = ws + 528896;                // 33 * 512
  float*  F3    = ws + 545792;                // 33 * 512
  float*  Ecat  = ws + 562688;                // 33 * 512
  int*    knn_i = (int*)(ws + 579584);        // 262144 ints
  float*  Mt    = ws + 841728;                // 262144 floats
  float*  Rm    = ws + 1103872;               // 262144 floats
  int*    cnt   = (int*)(ws + 1366016);       // 8 barrier counters

  prep_kernel<<<1024, 256, 0, stream>>>(inputs, knn_raw, w_mlp1, b_mlp1,
                                        w_lfa1, b_lfa1, w_lfa2, b_lfa2,
                                        w_mlp2, b_mlp2, w_res, b_res,
                                        knn_i, sbase, zbuf, Mt, Rm, cnt);
  chain_kernel<<<NCHAIN, 1024, 0, stream>>>(knn_i, sbase, zbuf, Rm, Mt,
                                            F2, F3, Ecat, cnt);
  out_kernel<<<256, 1024, 0, stream>>>(knn_i, sbase, Ecat, out);
}

// Round 12
// 218.273 us; speedup vs baseline: 2.2585x; 2.2585x over previous
//
#include <hip/hip_runtime.h>
#include <math.h>

#define NPTS 16384
#define KNB  16
#define D    512

// ---------------------------------------------------------------------------
// Closed-form restructure (verified rounds 1-11, absmax 0.0625). With
// S = gather-mean, R = Wres^T + I, M' = (W2c*W1)^T, per-block map
// f' = Cb + S^2 f M' + f R (f0 = 0), tracked in [33,512] coefficient space
// (rows 4k+c = component c of s_k, row 32 = bias):
//   F_1 = Cb33,   F_{t+1} = Cb33 + Shift2(F_t)*M' + F_t*R,   Ecat = F_4
// Final: out = [s0..s7,1] ([N,33]) x Ecat.
// Round 12: round-9 skeleton (8 plain dispatches — rounds 5/10/11 proved
// intra-kernel device barriers cost ~70us each on 8-XCD MI355X; kernel
// boundaries ~10us are strictly cheaper). Fix: hops at 8 thr/pt -> 128
// blocks; fstep (66-block layout, verified R10) rides H1/H3/H5 -> every
// dispatch <= 194 blocks < 256 CUs = single scheduling round, no tail.
// ---------------------------------------------------------------------------

// 1-hop gather-mean, 8 threads/point, 2 neighbors each (ILP), t < 131072
__device__ __forceinline__ void onehop8(int t, const int* __restrict__ knn,
                                        const float4* __restrict__ in,
                                        float4* __restrict__ out) {
  int n = t >> 3, k = t & 7;
  float4 g1 = in[knn[n * KNB + k]];
  float4 g2 = in[knn[n * KNB + k + 8]];
  float ax = g1.x + g2.x, ay = g1.y + g2.y;
  float az = g1.z + g2.z, aw = g1.w + g2.w;
#pragma unroll
  for (int o = 1; o < 8; o <<= 1) {
    ax += __shfl_xor(ax, o, 64); ay += __shfl_xor(ay, o, 64);
    az += __shfl_xor(az, o, 64); aw += __shfl_xor(aw, o, 64);
  }
  if (k == 0) {
    const float r = 1.f / 16.f;
    out[n] = make_float4(ax * r, ay * r, az * r, aw * r);
  }
}

__device__ __forceinline__ float4 red16(float ax, float ay, float az,
                                        float aw) {
#pragma unroll
  for (int o = 1; o < 16; o <<= 1) {
    ax += __shfl_xor(ax, o, 64); ay += __shfl_xor(ay, o, 64);
    az += __shfl_xor(az, o, 64); aw += __shfl_xor(aw, o, 64);
  }
  return make_float4(ax, ay, az, aw);
}

// One Horner step, 66-block layout (verified R10/R11): block fb handles row
// r = fb>>1, cols jbase..jbase+255 (jbase = (fb&1)*256). 1024 thr = 256 cols
// x 4 K-chunks of 128; LDS reduce; fp64 accumulate.
__device__ __forceinline__ void fstep66(
    int fb, int tid, int first, const float* __restrict__ Fprev,
    const float* __restrict__ zbuf, const float* __restrict__ Rm,
    const float* __restrict__ Mt, float* __restrict__ Fnext) {
  __shared__ double sA[512], sB[512];
  __shared__ double redm[4][256];
  const int r = fb >> 1, jbase = (fb & 1) * 256;
  const int rm = (r >= 8 && r < 32) ? (r - 8) : (r == 32 ? 32 : -1);
  if (tid < 512) {
    float v = first
        ? ((r < 8) ? zbuf[r * D + tid] : (r == 32 ? zbuf[8 * D + tid] : 0.f))
        : Fprev[r * D + tid];
    sA[tid] = (double)v;
  } else {
    int kk = tid - 512;
    float v = 0.f;
    if (rm >= 0)
      v = first ? ((rm < 8) ? zbuf[rm * D + kk]
                            : (rm == 32 ? zbuf[8 * D + kk] : 0.f))
                : Fprev[rm * D + kk];
    sB[kk] = (double)v;
  }
  __syncthreads();
  const int ol = tid & 255, kc = tid >> 8;
  const int j = jbase + ol, k0 = kc * 128;
  double a0 = 0.0, a1 = 0.0;
  for (int k = 0; k < 128; k += 2) {
    a0 += sA[k0 + k] * (double)Rm[(size_t)(k0 + k) * D + j] +
          sB[k0 + k] * (double)Mt[(size_t)(k0 + k) * D + j];
    a1 += sA[k0 + k + 1] * (double)Rm[(size_t)(k0 + k + 1) * D + j] +
          sB[k0 + k + 1] * (double)Mt[(size_t)(k0 + k + 1) * D + j];
  }
  redm[kc][ol] = a0 + a1;
  __syncthreads();
  if (kc == 0) {
    double s = redm[0][ol] + redm[1][ol] + redm[2][ol] + redm[3][ol];
    float cb = (r < 8) ? zbuf[r * D + j] : (r == 32 ? zbuf[8 * D + j] : 0.f);
    Fnext[r * D + j] = (float)(s + (double)cb);
  }
}

// ---- L0: knn normalize | geo (16 thr/pt) | pq(z) | Mt | Rm ----
__global__ __launch_bounds__(256) void prep_kernel(
    const float* __restrict__ pts, const int* __restrict__ raw,
    const float* __restrict__ w_mlp1, const float* __restrict__ b_mlp1,
    const float* __restrict__ w_lfa1, const float* __restrict__ b_lfa1,
    const float* __restrict__ w_lfa2, const float* __restrict__ b_lfa2,
    const float* __restrict__ w_mlp2, const float* __restrict__ b_mlp2,
    const float* __restrict__ w_res, const float* __restrict__ b_res,
    int* __restrict__ knn_i, float4* __restrict__ sbase,
    float* __restrict__ zbuf, float* __restrict__ Mt,
    float* __restrict__ Rm) {
  // int64 little-endian => odd words are zero high halves; (1/16384)^4 FP risk
  const bool is64 = (raw[1] == 0) && (raw[3] == 0) && (raw[5] == 0) &&
                    (raw[7] == 0);
  const int t = blockIdx.x * 256 + threadIdx.x;  // < 262144 == D*D
  knn_i[t] = is64 ? raw[2 * t] : raw[t];
  {  // geo: 16 threads/point
    int n = t >> 4, k = t & 15;
    int idx = is64 ? raw[2 * (n * KNB + k)] : raw[n * KNB + k];
    float dx = pts[n * 3 + 0] - pts[idx * 3 + 0];
    float dy = pts[n * 3 + 1] - pts[idx * 3 + 1];
    float dz = pts[n * 3 + 2] - pts[idx * 3 + 2];
    float nr = sqrtf(dx * dx + dy * dy + dz * dz);
    float4 s = red16(dx, dy, dz, nr);
    if (k == 0) {
      const float r = 1.f / 16.f;
      sbase[n] = make_float4(s.x * r, s.y * r, s.z * r, s.w * r);
    }
  }
  if (t < 32768) {  // pq: one wave per output column j; fp64 accumulate
    int j = t >> 6, lane = t & 63;
    const float* wrow = w_mlp2 + (size_t)j * D;
    double acc[9];
#pragma unroll
    for (int u = 0; u < 9; ++u) acc[u] = 0.0;
#pragma unroll
    for (int it = 0; it < 8; ++it) {
      int i = lane + 64 * it;
      double w = wrow[i];
      if (i < 256) {
        acc[0] += w * w_lfa2[i * 4 + 0]; acc[1] += w * w_lfa2[i * 4 + 1];
        acc[2] += w * w_lfa2[i * 4 + 2]; acc[3] += w * w_lfa2[i * 4 + 3];
        acc[8] += w * b_lfa2[i];
      } else if (i < 384) {
        int q = i - 256;
        acc[4] += w * w_lfa1[q * 4 + 0]; acc[5] += w * w_lfa1[q * 4 + 1];
        acc[6] += w * w_lfa1[q * 4 + 2]; acc[7] += w * w_lfa1[q * 4 + 3];
        acc[8] += w * b_lfa1[q];
      } else {
        acc[8] += w * b_mlp1[i - 384];
      }
    }
#pragma unroll
    for (int u = 0; u < 9; ++u) {
      double v = acc[u];
#pragma unroll
      for (int o = 32; o > 0; o >>= 1) v += __shfl_down(v, o, 64);
      if (lane == 0) {
        if (u == 8) v += (double)b_mlp2[j] + (double)b_res[j];
        zbuf[u * D + j] = (float)v;
      }
    }
  }
  {  // Mt[a*D+b] = sum_{i<128} w_mlp2[b][384+i]*w_mlp1[i][a]  (fp64 acc)
    int a = t & 511, b = t >> 9;
    const float* wrow = w_mlp2 + (size_t)b * D + 384;
    double s0 = 0.0, s1 = 0.0, s2 = 0.0, s3 = 0.0;
#pragma unroll 8
    for (int i = 0; i < 128; i += 4) {
      s0 += (double)wrow[i + 0] * (double)w_mlp1[(size_t)(i + 0) * D + a];
      s1 += (double)wrow[i + 1] * (double)w_mlp1[(size_t)(i + 1) * D + a];
      s2 += (double)wrow[i + 2] * (double)w_mlp1[(size_t)(i + 2) * D + a];
      s3 += (double)wrow[i + 3] * (double)w_mlp1[(size_t)(i + 3) * D + a];
    }
    Mt[(size_t)a * D + b] = (float)((s0 + s1) + (s2 + s3));
  }
  {  // Rm[i*D+j] = w_res[j][i] + (i==j)
    int i = t & 511, j = t >> 9;
    Rm[(size_t)i * D + j] = w_res[(size_t)j * D + i] + ((i == j) ? 1.0f : 0.0f);
  }
}

// ---- H1..H6: 1-hop (blocks 0..127, 8 thr/pt) | fstep66 (blocks 128..193,
//      only in H1/H3/H5) — max 194 blocks = single scheduling round ----
__global__ __launch_bounds__(1024) void hop_kernel(
    const int* __restrict__ knn, const float4* __restrict__ sin,
    float4* __restrict__ sout, const float* __restrict__ zbuf,
    const float* __restrict__ Rm, const float* __restrict__ Mt,
    const float* __restrict__ Fprev, float* __restrict__ Fnext, int first) {
  const int tid = threadIdx.x;
  if (blockIdx.x < 128) {
    onehop8(blockIdx.x * 1024 + tid, knn, sin, sout);
  } else {
    fstep66((int)blockIdx.x - 128, tid, first, Fprev, zbuf, Rm, Mt, Fnext);
  }
}

// ---- L4: out[n][:] = [s0..s7,1][n] x Ecat; s7 inline (1-hop from s6) ----
__global__ __launch_bounds__(1024, 4) void out_kernel(
    const int* __restrict__ knn, const float4* __restrict__ sbase,
    const float* __restrict__ Ecat, float* __restrict__ outp) {
  const int tid = threadIdx.x;
  const int n0 = blockIdx.x * 64;
  __shared__ float4 s_t[8][64];
  {  // s7 for this block's 64 points: 16 threads/point
    int pt = tid >> 4, k = tid & 15;
    float4 g = sbase[(size_t)6 * NPTS + knn[(n0 + pt) * KNB + k]];
    float4 s = red16(g.x, g.y, g.z, g.w);
    if (k == 0) {
      const float r = 1.f / 16.f;
      s_t[7][pt] = make_float4(s.x * r, s.y * r, s.z * r, s.w * r);
    }
  }
  if (tid < 448) {  // load s0..s6 tiles
    int k = tid / 64, pt = tid & 63;
    s_t[k][pt] = sbase[(size_t)k * NPTS + n0 + pt];
  }
  __syncthreads();
  const int col2 = tid & 255;  // this thread's float2 column
  const int ptg = tid >> 8;    // 0..3
  float2 tab[33];
#pragma unroll
  for (int r = 0; r < 33; ++r)
    tab[r] = *(const float2*)(Ecat + r * D + col2 * 2);
#pragma unroll
  for (int it = 0; it < 16; ++it) {
    int pt = ptg * 16 + it;
    float2 acc = tab[32];
#pragma unroll
    for (int k = 0; k < 8; ++k) {
      float4 s = s_t[k][pt];  // wave-uniform LDS broadcast
      float2 e0 = tab[4 * k + 0], e1 = tab[4 * k + 1];
      float2 e2 = tab[4 * k + 2], e3 = tab[4 * k + 3];
      acc.x += s.x * e0.x + s.y * e1.x + s.z * e2.x + s.w * e3.x;
      acc.y += s.x * e0.y + s.y * e1.y + s.z * e2.y + s.w * e3.y;
    }
    *(float2*)(outp + (size_t)(n0 + pt) * D + col2 * 2) = acc;
  }
}

extern "C" void kernel_launch(void* const* d_in, const int* in_sizes, int n_in,
                              void* d_out, int out_size, void* d_ws,
                              size_t ws_size, hipStream_t stream) {
  const float* inputs = (const float*)d_in[0];
  const int* knn_raw  = (const int*)d_in[1];
  const float* w_mlp1 = (const float*)d_in[2];
  const float* b_mlp1 = (const float*)d_in[3];
  const float* w_lfa1 = (const float*)d_in[4];
  const float* b_lfa1 = (const float*)d_in[5];
  const float* w_lfa2 = (const float*)d_in[6];
  const float* b_lfa2 = (const float*)d_in[7];
  const float* w_mlp2 = (const float*)d_in[8];
  const float* b_mlp2 = (const float*)d_in[9];
  const float* w_res  = (const float*)d_in[10];
  const float* b_res  = (const float*)d_in[11];
  float* out = (float*)d_out;

  // workspace (floats): ~5.5 MB
  float*  ws    = (float*)d_ws;
  float4* sbase = (float4*)(ws + 0);          // 8 * 16384 float4
  float*  zbuf  = ws + 524288;                // 9 * 512
  float*  F2    = ws + 528896;                // 33 * 512
  float*  F3    = ws + 545792;                // 33 * 512
  float*  Ecat  = ws + 562688;                // 33 * 512
  int*    knn_i = (int*)(ws + 579584);        // 262144 ints
  float*  Mt    = ws + 841728;                // 262144 floats
  float*  Rm    = ws + 1103872;               // 262144 floats

  prep_kernel<<<1024, 256, 0, stream>>>(inputs, knn_raw, w_mlp1, b_mlp1,
                                        w_lfa1, b_lfa1, w_lfa2, b_lfa2,
                                        w_mlp2, b_mlp2, w_res, b_res,
                                        knn_i, sbase, zbuf, Mt, Rm);
  float4* s0 = (float4*)sbase;
  // H1: s1 = S s0 | fstep1: F2 = step(Cb)
  hop_kernel<<<194, 1024, 0, stream>>>(knn_i, s0, s0 + NPTS, zbuf, Rm, Mt,
                                       (const float*)nullptr, F2, 1);
  // H2: s2 = S s1
  hop_kernel<<<128, 1024, 0, stream>>>(knn_i, s0 + NPTS, s0 + 2 * NPTS, zbuf,
                                       Rm, Mt, (const float*)nullptr,
                                       (float*)nullptr, 0);
  // H3: s3 = S s2 | fstep2: F3 = step(F2)
  hop_kernel<<<194, 1024, 0, stream>>>(knn_i, s0 + 2 * NPTS, s0 + 3 * NPTS,
                                       zbuf, Rm, Mt, F2, F3, 0);
  // H4: s4 = S s3
  hop_kernel<<<128, 1024, 0, stream>>>(knn_i, s0 + 3 * NPTS, s0 + 4 * NPTS,
                                       zbuf, Rm, Mt, (const float*)nullptr,
                                       (float*)nullptr, 0);
  // H5: s5 = S s4 | fstep3: Ecat = F4 = step(F3)
  hop_kernel<<<194, 1024, 0, stream>>>(knn_i, s0 + 4 * NPTS, s0 + 5 * NPTS,
                                       zbuf, Rm, Mt, F3, Ecat, 0);
  // H6: s6 = S s5
  hop_kernel<<<128, 1024, 0, stream>>>(knn_i, s0 + 5 * NPTS, s0 + 6 * NPTS,
                                       zbuf, Rm, Mt, (const float*)nullptr,
                                       (float*)nullptr, 0);
  // L4: out (s7 inline)
  out_kernel<<<256, 1024, 0, stream>>>(knn_i, sbase, Ecat, out);
}

// Round 13
// 159.075 us; speedup vs baseline: 3.0990x; 1.3721x over previous
//
#include <hip/hip_runtime.h>
#include <math.h>

#define NPTS 16384
#define KNB  16
#define D    512

// ---------------------------------------------------------------------------
// Closed-form restructure (verified rounds 1-12, absmax 0.0625). With
// S = gather-mean, R = Wres^T + I, M' = (W2c*W1)^T, per-block map
// f' = Cb + S^2 f M' + f R (f0 = 0), tracked in [33,512] coefficient space
// (rows 4k+c = component c of s_k, row 32 = bias):
//   F_1 = Cb33,   F_{t+1} = Cb33 + Shift2(F_t)*M' + F_t*R,   Ecat = F_4
// Final: out = [s0..s7,1] ([N,33]) x Ecat.
// Round 13: R12 skeleton (8 dispatches; in-kernel device barriers cost ~70us
// on 8-XCD MI355X — never again). Fix R12's regression: fstep66's 256 scalar
// loads/thread (47us dispatches) -> float4 loads, 4 cols/thread, 8 FMA
// chains, 64 loads/thread. Hops unchanged (onehop8, 128 blocks).
// ---------------------------------------------------------------------------

// 1-hop gather-mean, 8 threads/point, 2 neighbors each (ILP), t < 131072
__device__ __forceinline__ void onehop8(int t, const int* __restrict__ knn,
                                        const float4* __restrict__ in,
                                        float4* __restrict__ out) {
  int n = t >> 3, k = t & 7;
  float4 g1 = in[knn[n * KNB + k]];
  float4 g2 = in[knn[n * KNB + k + 8]];
  float ax = g1.x + g2.x, ay = g1.y + g2.y;
  float az = g1.z + g2.z, aw = g1.w + g2.w;
#pragma unroll
  for (int o = 1; o < 8; o <<= 1) {
    ax += __shfl_xor(ax, o, 64); ay += __shfl_xor(ay, o, 64);
    az += __shfl_xor(az, o, 64); aw += __shfl_xor(aw, o, 64);
  }
  if (k == 0) {
    const float r = 1.f / 16.f;
    out[n] = make_float4(ax * r, ay * r, az * r, aw * r);
  }
}

__device__ __forceinline__ float4 red16(float ax, float ay, float az,
                                        float aw) {
#pragma unroll
  for (int o = 1; o < 16; o <<= 1) {
    ax += __shfl_xor(ax, o, 64); ay += __shfl_xor(ay, o, 64);
    az += __shfl_xor(az, o, 64); aw += __shfl_xor(aw, o, 64);
  }
  return make_float4(ax, ay, az, aw);
}

// One Horner step, 66 blocks: block fb -> row r = fb>>1, cols
// jbase..jbase+255 (jbase = (fb&1)*256). Threads: 64 col-quads x 16 k-chunks
// of 32. float4 loads of Rm/Mt (1KB/wave-inst), acc[4] fp64 per thread,
// LDS reduce over k-chunks. fp64 accumulate (verified numerics).
__device__ __forceinline__ void fstep66(
    int fb, int tid, int first, const float* __restrict__ Fprev,
    const float* __restrict__ zbuf, const float* __restrict__ Rm,
    const float* __restrict__ Mt, float* __restrict__ Fnext) {
  __shared__ float sA[512], sB[512];
  __shared__ double redm[16][256];
  const int r = fb >> 1, jbase = (fb & 1) * 256;
  const int rm = (r >= 8 && r < 32) ? (r - 8) : (r == 32 ? 32 : -1);
  if (tid < 512) {
    sA[tid] = first
        ? ((r < 8) ? zbuf[r * D + tid] : (r == 32 ? zbuf[8 * D + tid] : 0.f))
        : Fprev[r * D + tid];
  } else {
    int kk = tid - 512;
    float v = 0.f;
    if (rm >= 0)
      v = first ? ((rm < 8) ? zbuf[rm * D + kk]
                            : (rm == 32 ? zbuf[8 * D + kk] : 0.f))
                : Fprev[rm * D + kk];
    sB[kk] = v;
  }
  __syncthreads();
  const int q = tid & 63, kc = tid >> 6;   // col-quad, k-chunk
  const int j0 = jbase + q * 4, k0 = kc * 32;
  double a0 = 0, a1 = 0, a2 = 0, a3 = 0;
#pragma unroll 2
  for (int k = 0; k < 32; ++k) {
    const float4 rv = *(const float4*)(Rm + (size_t)(k0 + k) * D + j0);
    const float4 mv = *(const float4*)(Mt + (size_t)(k0 + k) * D + j0);
    const double a = (double)sA[k0 + k], b = (double)sB[k0 + k];
    a0 += a * (double)rv.x + b * (double)mv.x;
    a1 += a * (double)rv.y + b * (double)mv.y;
    a2 += a * (double)rv.z + b * (double)mv.z;
    a3 += a * (double)rv.w + b * (double)mv.w;
  }
  redm[kc][q * 4 + 0] = a0; redm[kc][q * 4 + 1] = a1;
  redm[kc][q * 4 + 2] = a2; redm[kc][q * 4 + 3] = a3;
  __syncthreads();
  if (tid < 256) {
    double s = 0.0;
#pragma unroll
    for (int u = 0; u < 16; ++u) s += redm[u][tid];
    int j = jbase + tid;
    float cb = (r < 8) ? zbuf[r * D + j] : (r == 32 ? zbuf[8 * D + j] : 0.f);
    Fnext[r * D + j] = (float)(s + (double)cb);
  }
}

// ---- L0: knn normalize | geo (16 thr/pt) | pq(z) | Mt | Rm ----
__global__ __launch_bounds__(256) void prep_kernel(
    const float* __restrict__ pts, const int* __restrict__ raw,
    const float* __restrict__ w_mlp1, const float* __restrict__ b_mlp1,
    const float* __restrict__ w_lfa1, const float* __restrict__ b_lfa1,
    const float* __restrict__ w_lfa2, const float* __restrict__ b_lfa2,
    const float* __restrict__ w_mlp2, const float* __restrict__ b_mlp2,
    const float* __restrict__ w_res, const float* __restrict__ b_res,
    int* __restrict__ knn_i, float4* __restrict__ sbase,
    float* __restrict__ zbuf, float* __restrict__ Mt,
    float* __restrict__ Rm) {
  // int64 little-endian => odd words are zero high halves; (1/16384)^4 FP risk
  const bool is64 = (raw[1] == 0) && (raw[3] == 0) && (raw[5] == 0) &&
                    (raw[7] == 0);
  const int t = blockIdx.x * 256 + threadIdx.x;  // < 262144 == D*D
  knn_i[t] = is64 ? raw[2 * t] : raw[t];
  {  // geo: 16 threads/point
    int n = t >> 4, k = t & 15;
    int idx = is64 ? raw[2 * (n * KNB + k)] : raw[n * KNB + k];
    float dx = pts[n * 3 + 0] - pts[idx * 3 + 0];
    float dy = pts[n * 3 + 1] - pts[idx * 3 + 1];
    float dz = pts[n * 3 + 2] - pts[idx * 3 + 2];
    float nr = sqrtf(dx * dx + dy * dy + dz * dz);
    float4 s = red16(dx, dy, dz, nr);
    if (k == 0) {
      const float r = 1.f / 16.f;
      sbase[n] = make_float4(s.x * r, s.y * r, s.z * r, s.w * r);
    }
  }
  if (t < 32768) {  // pq: one wave per output column j; fp64 accumulate
    int j = t >> 6, lane = t & 63;
    const float* wrow = w_mlp2 + (size_t)j * D;
    double acc[9];
#pragma unroll
    for (int u = 0; u < 9; ++u) acc[u] = 0.0;
#pragma unroll
    for (int it = 0; it < 8; ++it) {
      int i = lane + 64 * it;
      double w = wrow[i];
      if (i < 256) {
        acc[0] += w * w_lfa2[i * 4 + 0]; acc[1] += w * w_lfa2[i * 4 + 1];
        acc[2] += w * w_lfa2[i * 4 + 2]; acc[3] += w * w_lfa2[i * 4 + 3];
        acc[8] += w * b_lfa2[i];
      } else if (i < 384) {
        int q = i - 256;
        acc[4] += w * w_lfa1[q * 4 + 0]; acc[5] += w * w_lfa1[q * 4 + 1];
        acc[6] += w * w_lfa1[q * 4 + 2]; acc[7] += w * w_lfa1[q * 4 + 3];
        acc[8] += w * b_lfa1[q];
      } else {
        acc[8] += w * b_mlp1[i - 384];
      }
    }
#pragma unroll
    for (int u = 0; u < 9; ++u) {
      double v = acc[u];
#pragma unroll
      for (int o = 32; o > 0; o >>= 1) v += __shfl_down(v, o, 64);
      if (lane == 0) {
        if (u == 8) v += (double)b_mlp2[j] + (double)b_res[j];
        zbuf[u * D + j] = (float)v;
      }
    }
  }
  {  // Mt[a*D+b] = sum_{i<128} w_mlp2[b][384+i]*w_mlp1[i][a]  (fp64 acc)
    int a = t & 511, b = t >> 9;
    const float* wrow = w_mlp2 + (size_t)b * D + 384;
    double s0 = 0.0, s1 = 0.0, s2 = 0.0, s3 = 0.0;
#pragma unroll 8
    for (int i = 0; i < 128; i += 4) {
      s0 += (double)wrow[i + 0] * (double)w_mlp1[(size_t)(i + 0) * D + a];
      s1 += (double)wrow[i + 1] * (double)w_mlp1[(size_t)(i + 1) * D + a];
      s2 += (double)wrow[i + 2] * (double)w_mlp1[(size_t)(i + 2) * D + a];
      s3 += (double)wrow[i + 3] * (double)w_mlp1[(size_t)(i + 3) * D + a];
    }
    Mt[(size_t)a * D + b] = (float)((s0 + s1) + (s2 + s3));
  }
  {  // Rm[i*D+j] = w_res[j][i] + (i==j)
    int i = t & 511, j = t >> 9;
    Rm[(size_t)i * D + j] = w_res[(size_t)j * D + i] + ((i == j) ? 1.0f : 0.0f);
  }
}

// ---- H1..H6: 1-hop (blocks 0..127, 8 thr/pt) | fstep66 (blocks 128..193,
//      only in H1/H3/H5) — max 194 blocks = single scheduling round ----
__global__ __launch_bounds__(1024) void hop_kernel(
    const int* __restrict__ knn, const float4* __restrict__ sin,
    float4* __restrict__ sout, const float* __restrict__ zbuf,
    const float* __restrict__ Rm, const float* __restrict__ Mt,
    const float* __restrict__ Fprev, float* __restrict__ Fnext, int first) {
  const int tid = threadIdx.x;
  if (blockIdx.x < 128) {
    onehop8(blockIdx.x * 1024 + tid, knn, sin, sout);
  } else {
    fstep66((int)blockIdx.x - 128, tid, first, Fprev, zbuf, Rm, Mt, Fnext);
  }
}

// ---- L4: out[n][:] = [s0..s7,1][n] x Ecat; s7 inline (1-hop from s6) ----
__global__ __launch_bounds__(1024, 4) void out_kernel(
    const int* __restrict__ knn, const float4* __restrict__ sbase,
    const float* __restrict__ Ecat, float* __restrict__ outp) {
  const int tid = threadIdx.x;
  const int n0 = blockIdx.x * 64;
  __shared__ float4 s_t[8][64];
  {  // s7 for this block's 64 points: 16 threads/point
    int pt = tid >> 4, k = tid & 15;
    float4 g = sbase[(size_t)6 * NPTS + knn[(n0 + pt) * KNB + k]];
    float4 s = red16(g.x, g.y, g.z, g.w);
    if (k == 0) {
      const float r = 1.f / 16.f;
      s_t[7][pt] = make_float4(s.x * r, s.y * r, s.z * r, s.w * r);
    }
  }
  if (tid < 448) {  // load s0..s6 tiles
    int k = tid / 64, pt = tid & 63;
    s_t[k][pt] = sbase[(size_t)k * NPTS + n0 + pt];
  }
  __syncthreads();
  const int col2 = tid & 255;  // this thread's float2 column
  const int ptg = tid >> 8;    // 0..3
  float2 tab[33];
#pragma unroll
  for (int r = 0; r < 33; ++r)
    tab[r] = *(const float2*)(Ecat + r * D + col2 * 2);
#pragma unroll
  for (int it = 0; it < 16; ++it) {
    int pt = ptg * 16 + it;
    float2 acc = tab[32];
#pragma unroll
    for (int k = 0; k < 8; ++k) {
      float4 s = s_t[k][pt];  // wave-uniform LDS broadcast
      float2 e0 = tab[4 * k + 0], e1 = tab[4 * k + 1];
      float2 e2 = tab[4 * k + 2], e3 = tab[4 * k + 3];
      acc.x += s.x * e0.x + s.y * e1.x + s.z * e2.x + s.w * e3.x;
      acc.y += s.x * e0.y + s.y * e1.y + s.z * e2.y + s.w * e3.y;
    }
    *(float2*)(outp + (size_t)(n0 + pt) * D + col2 * 2) = acc;
  }
}

extern "C" void kernel_launch(void* const* d_in, const int* in_sizes, int n_in,
                              void* d_out, int out_size, void* d_ws,
                              size_t ws_size, hipStream_t stream) {
  const float* inputs = (const float*)d_in[0];
  const int* knn_raw  = (const int*)d_in[1];
  const float* w_mlp1 = (const float*)d_in[2];
  const float* b_mlp1 = (const float*)d_in[3];
  const float* w_lfa1 = (const float*)d_in[4];
  const float* b_lfa1 = (const float*)d_in[5];
  const float* w_lfa2 = (const float*)d_in[6];
  const float* b_lfa2 = (const float*)d_in[7];
  const float* w_mlp2 = (const float*)d_in[8];
  const float* b_mlp2 = (const float*)d_in[9];
  const float* w_res  = (const float*)d_in[10];
  const float* b_res  = (const float*)d_in[11];
  float* out = (float*)d_out;

  // workspace (floats): ~5.5 MB
  float*  ws    = (float*)d_ws;
  float4* sbase = (float4*)(ws + 0);          // 8 * 16384 float4
  float*  zbuf  = ws + 524288;                // 9 * 512
  float*  F2    = ws + 528896;                // 33 * 512
  float*  F3    = ws + 545792;                // 33 * 512
  float*  Ecat  = ws + 562688;                // 33 * 512
  int*    knn_i = (int*)(ws + 579584);        // 262144 ints
  float*  Mt    = ws + 841728;                // 262144 floats
  float*  Rm    = ws + 1103872;               // 262144 floats

  prep_kernel<<<1024, 256, 0, stream>>>(inputs, knn_raw, w_mlp1, b_mlp1,
                                        w_lfa1, b_lfa1, w_lfa2, b_lfa2,
                                        w_mlp2, b_mlp2, w_res, b_res,
                                        knn_i, sbase, zbuf, Mt, Rm);
  float4* s0 = (float4*)sbase;
  // H1: s1 = S s0 | fstep1: F2 = step(Cb)
  hop_kernel<<<194, 1024, 0, stream>>>(knn_i, s0, s0 + NPTS, zbuf, Rm, Mt,
                                       (const float*)nullptr, F2, 1);
  // H2: s2 = S s1
  hop_kernel<<<128, 1024, 0, stream>>>(knn_i, s0 + NPTS, s0 + 2 * NPTS, zbuf,
                                       Rm, Mt, (const float*)nullptr,
                                       (float*)nullptr, 0);
  // H3: s3 = S s2 | fstep2: F3 = step(F2)
  hop_kernel<<<194, 1024, 0, stream>>>(knn_i, s0 + 2 * NPTS, s0 + 3 * NPTS,
                                       zbuf, Rm, Mt, F2, F3, 0);
  // H4: s4 = S s3
  hop_kernel<<<128, 1024, 0, stream>>>(knn_i, s0 + 3 * NPTS, s0 + 4 * NPTS,
                                       zbuf, Rm, Mt, (const float*)nullptr,
                                       (float*)nullptr, 0);
  // H5: s5 = S s4 | fstep3: Ecat = F4 = step(F3)
  hop_kernel<<<194, 1024, 0, stream>>>(knn_i, s0 + 4 * NPTS, s0 + 5 * NPTS,
                                       zbuf, Rm, Mt, F3, Ecat, 0);
  // H6: s6 = S s5
  hop_kernel<<<128, 1024, 0, stream>>>(knn_i, s0 + 5 * NPTS, s0 + 6 * NPTS,
                                       zbuf, Rm, Mt, (const float*)nullptr,
                                       (float*)nullptr, 0);
  // L4: out (s7 inline)
  out_kernel<<<256, 1024, 0, stream>>>(knn_i, sbase, Ecat, out);
}